// Round 1
// baseline (447.032 us; speedup 1.0000x reference)
//
#include <hip/hip_runtime.h>

// Quantum circuit simulator: 18 wires, 3 layers, batch 64.
// State kept in-place as SoA planes in d_in[0] (re) / d_in[1] (im).
// Wire w <-> bit p = 17-w. Per layer (exact rewrite via commutation):
//   PassB: SQ(bits 17..11), CNOT(17,16)..(12,11)   [touches bits 11..17]
//   PassA: SQ(bits 10..0),  CNOT(11,10)..(1,0)     [touches bits 0..11]
// SQ = fused RY(θy) then RZ(θz) with RZ global phase dropped (output is |amp|^2 only):
//   (a,b) -> (c*a - s*b, e^{iθz}*(s*a + c*b)),  c=cos(θy/2), s=sin(θy/2)
// Final PassA also computes feats·head_w + head_b via sign-split accumulators.

static __device__ __forceinline__ int phys(int m) {
    // LDS skew: keeps 16B alignment (multiple-of-4 shift), breaks power-of-2 bank strides
    return m + 4 * ((m >> 6) + (m >> 9));
}

template<int J>
__device__ __forceinline__ void sqg(float* ar, float* ai, float c, float s, float pc, float ps) {
#pragma unroll
    for (int r = 0; r < 32; ++r) {
        if (((r >> J) & 1) == 0) {
            const int r1 = r + (1 << J);
            const float a0r = ar[r], a0i = ai[r], a1r = ar[r1], a1i = ai[r1];
            ar[r] = fmaf(c, a0r, -(s * a1r));
            ai[r] = fmaf(c, a0i, -(s * a1i));
            const float t1r = fmaf(s, a0r, c * a1r);
            const float t1i = fmaf(s, a0i, c * a1i);
            ar[r1] = fmaf(pc, t1r, -(ps * t1i));
            ai[r1] = fmaf(pc, t1i,  (ps * t1r));
        }
    }
}

template<int JC, int JT>
__device__ __forceinline__ void cnotg(float* ar, float* ai) {
#pragma unroll
    for (int r = 0; r < 32; ++r) {
        if (((r >> JC) & 1) == 1 && ((r >> JT) & 1) == 0) {
            const int r1 = r + (1 << JT);
            float tr = ar[r]; ar[r] = ar[r1]; ar[r1] = tr;
            float ti = ai[r]; ai[r] = ai[r1]; ai[r1] = ti;
        }
    }
}

// ---------------- Pass B: bits 11..17 ----------------
// Block covers bits {11..17} x filler {0..4}; fixed bits: batch, mid = bits 5..10.
__global__ __launch_bounds__(128) void passB_k(float* __restrict__ re, float* __restrict__ im,
                                               const float* __restrict__ params, int layer)
{
    __shared__ float lre[4384], lim[4384];
    const int t    = threadIdx.x;
    const int b    = blockIdx.x >> 6;
    const int mid  = blockIdx.x & 63;
    const int base = (b << 18) | (mid << 5);

    // coeffs for bit 11+k  (wire 6-k)
    float C[7], S[7], PC[7], PS[7];
    const float* pl = params + layer * 36;
#pragma unroll
    for (int k = 0; k < 7; ++k) {
        const int w = 6 - k;
        __sincosf(0.5f * pl[w], &S[k], &C[k]);
        __sincosf(pl[18 + w], &PS[k], &PC[k]);
    }

    float ar[32], ai[32];
    // B1 layout: reg = bits 13..17 ; cols: t&31 = bits 0..4, t>>5 = bits 11,12
#pragma unroll
    for (int r = 0; r < 32; ++r) {
        const int n = base + (r << 13) + ((t >> 5) << 11) + (t & 31);
        ar[r] = re[n]; ai[r] = im[n];
    }
    // SQ(17..13), CNOT(17,16)..(14,13)   (reg bit j = global bit 13+j = coeff j+2)
    sqg<4>(ar, ai, C[6], S[6], PC[6], PS[6]);
    sqg<3>(ar, ai, C[5], S[5], PC[5], PS[5]);
    sqg<2>(ar, ai, C[4], S[4], PC[4], PS[4]);
    sqg<1>(ar, ai, C[3], S[3], PC[3], PS[3]);
    sqg<0>(ar, ai, C[2], S[2], PC[2], PS[2]);
    cnotg<4,3>(ar, ai);
    cnotg<3,2>(ar, ai);
    cnotg<2,1>(ar, ai);
    cnotg<1,0>(ar, ai);

    // T1: local m = (bits 11..17)<<5 | (bits 0..4) = r<<7 | t
#pragma unroll
    for (int r = 0; r < 32; ++r) {
        const int m = (r << 7) | t;
        lre[phys(m)] = ar[r]; lim[phys(m)] = ai[r];
    }
    __syncthreads();
    // B2 layout: reg r&3 = bits 0,1 ; reg r>>2 = bits 11,12,13 ; cols: t&7 = bits 2..4, t>>3 = bits 14..17
#pragma unroll
    for (int g = 0; g < 8; ++g) {
        const int m = ((t >> 3) << 8) | (g << 5) | ((t & 7) << 2);
        const float4 vr = *(const float4*)&lre[phys(m)];
        const float4 vi = *(const float4*)&lim[phys(m)];
        ar[4*g+0] = vr.x; ar[4*g+1] = vr.y; ar[4*g+2] = vr.z; ar[4*g+3] = vr.w;
        ai[4*g+0] = vi.x; ai[4*g+1] = vi.y; ai[4*g+2] = vi.z; ai[4*g+3] = vi.w;
    }
    // SQ(12)=reg3, SQ(11)=reg2, CNOT(13,12)=<4,3>, CNOT(12,11)=<3,2>
    sqg<3>(ar, ai, C[1], S[1], PC[1], PS[1]);
    sqg<2>(ar, ai, C[0], S[0], PC[0], PS[0]);
    cnotg<4,3>(ar, ai);
    cnotg<3,2>(ar, ai);

    // store directly from B2 layout (float4, 128B segments)
#pragma unroll
    for (int g = 0; g < 8; ++g) {
        const int n = base + ((t >> 3) << 14) + (g << 11) + ((t & 7) << 2);
        *(float4*)&re[n] = make_float4(ar[4*g+0], ar[4*g+1], ar[4*g+2], ar[4*g+3]);
        *(float4*)&im[n] = make_float4(ai[4*g+0], ai[4*g+1], ai[4*g+2], ai[4*g+3]);
    }
}

// ---------------- Pass A: bits 0..11 ----------------
// Block covers bits {0..11}; fixed bits: batch, hi = bits 12..17.
template<bool FINAL>
__global__ __launch_bounds__(128) void passA_k(float* __restrict__ re, float* __restrict__ im,
                                               const float* __restrict__ params, int layer,
                                               const float* __restrict__ hw,
                                               const float* __restrict__ hb,
                                               float* __restrict__ out)
{
    __shared__ float lre[4384], lim[4384];
    const int t    = threadIdx.x;
    const int b    = blockIdx.x >> 6;
    const int hi   = blockIdx.x & 63;
    const int base = (b << 18) | (hi << 12);

    // coeffs for bit p (wire 17-p), p = 0..10
    float C[11], S[11], PC[11], PS[11];
    const float* pl = params + layer * 36;
#pragma unroll
    for (int p = 0; p < 11; ++p) {
        const int w = 17 - p;
        __sincosf(0.5f * pl[w], &S[p], &C[p]);
        __sincosf(pl[18 + w], &PS[p], &PC[p]);
    }

    float ar[32], ai[32];
    // A1 layout: reg = bits 7..11 ; cols t = bits 0..6
#pragma unroll
    for (int r = 0; r < 32; ++r) {
        const int n = base + (r << 7) + t;
        ar[r] = re[n]; ai[r] = im[n];
    }
    // SQ(10..7), CNOT(11,10)..(8,7)   (reg j = global 7+j)
    sqg<3>(ar, ai, C[10], S[10], PC[10], PS[10]);
    sqg<2>(ar, ai, C[9],  S[9],  PC[9],  PS[9]);
    sqg<1>(ar, ai, C[8],  S[8],  PC[8],  PS[8]);
    sqg<0>(ar, ai, C[7],  S[7],  PC[7],  PS[7]);
    cnotg<4,3>(ar, ai); cnotg<3,2>(ar, ai); cnotg<2,1>(ar, ai); cnotg<1,0>(ar, ai);

    // T1 -> A2 layout: reg = bits 3..7 ; cols: t&7 = bits 0..2, t>>3 = bits 8..11
#pragma unroll
    for (int r = 0; r < 32; ++r) {
        const int m = (r << 7) | t;
        lre[phys(m)] = ar[r]; lim[phys(m)] = ai[r];
    }
    __syncthreads();
#pragma unroll
    for (int r = 0; r < 32; ++r) {
        const int m = ((t >> 3) << 8) | (r << 3) | (t & 7);
        ar[r] = lre[phys(m)]; ai[r] = lim[phys(m)];
    }
    // SQ(6..3), CNOT(7,6)..(4,3)   (reg j = global 3+j)
    sqg<3>(ar, ai, C[6], S[6], PC[6], PS[6]);
    sqg<2>(ar, ai, C[5], S[5], PC[5], PS[5]);
    sqg<1>(ar, ai, C[4], S[4], PC[4], PS[4]);
    sqg<0>(ar, ai, C[3], S[3], PC[3], PS[3]);
    cnotg<4,3>(ar, ai); cnotg<3,2>(ar, ai); cnotg<2,1>(ar, ai); cnotg<1,0>(ar, ai);

    // T2 -> A3 layout: reg = bits 0..4 ; cols t = bits 5..11
    __syncthreads();
#pragma unroll
    for (int r = 0; r < 32; ++r) {
        const int m = ((t >> 3) << 8) | (r << 3) | (t & 7);
        lre[phys(m)] = ar[r]; lim[phys(m)] = ai[r];
    }
    __syncthreads();
#pragma unroll
    for (int g = 0; g < 8; ++g) {
        const int m = (t << 5) | (g << 2);
        const float4 vr = *(const float4*)&lre[phys(m)];
        const float4 vi = *(const float4*)&lim[phys(m)];
        ar[4*g+0] = vr.x; ar[4*g+1] = vr.y; ar[4*g+2] = vr.z; ar[4*g+3] = vr.w;
        ai[4*g+0] = vi.x; ai[4*g+1] = vi.y; ai[4*g+2] = vi.z; ai[4*g+3] = vi.w;
    }
    // SQ(2..0), CNOT(3,2),(2,1),(1,0)  (reg j = global j)
    sqg<2>(ar, ai, C[2], S[2], PC[2], PS[2]);
    sqg<1>(ar, ai, C[1], S[1], PC[1], PS[1]);
    sqg<0>(ar, ai, C[0], S[0], PC[0], PS[0]);
    cnotg<3,2>(ar, ai); cnotg<2,1>(ar, ai); cnotg<1,0>(ar, ai);

    if (!FINAL) {
        // T3 -> store layout: reg r&3 = bits 0,1 ; reg r>>2 = bits 9,10,11 ; cols t = bits 2..8
        __syncthreads();
#pragma unroll
        for (int g = 0; g < 8; ++g) {
            const int m = (t << 5) | (g << 2);
            *(float4*)&lre[phys(m)] = make_float4(ar[4*g+0], ar[4*g+1], ar[4*g+2], ar[4*g+3]);
            *(float4*)&lim[phys(m)] = make_float4(ai[4*g+0], ai[4*g+1], ai[4*g+2], ai[4*g+3]);
        }
        __syncthreads();
#pragma unroll
        for (int g = 0; g < 8; ++g) {
            const int m = (g << 9) | (t << 2);
            const float4 vr = *(const float4*)&lre[phys(m)];
            const float4 vi = *(const float4*)&lim[phys(m)];
            const int n = base + (g << 9) + (t << 2);
            *(float4*)&re[n] = vr;
            *(float4*)&im[n] = vi;
        }
    } else {
        // expval(Z_w) for all wires + linear head, from A3 layout: n = base | (t<<5) | r
        float accP = 0.f, D0 = 0.f, D1 = 0.f, D2 = 0.f, D3 = 0.f, D4 = 0.f;
#pragma unroll
        for (int r = 0; r < 32; ++r) {
            const float p = ar[r] * ar[r] + ai[r] * ai[r];
            accP += p;
            if (r & 1)  D0 -= p; else D0 += p;
            if (r & 2)  D1 -= p; else D1 += p;
            if (r & 4)  D2 -= p; else D2 += p;
            if (r & 8)  D3 -= p; else D3 += p;
            if (r & 16) D4 -= p; else D4 += p;
        }
        float G = 0.f;
#pragma unroll
        for (int k = 0; k < 7; ++k)   // n bit 5+k = t bit k, wire 12-k
            G += ((t >> k) & 1) ? -hw[12 - k] : hw[12 - k];
#pragma unroll
        for (int k = 0; k < 6; ++k)   // n bit 12+k = hi bit k, wire 5-k
            G += ((hi >> k) & 1) ? -hw[5 - k] : hw[5 - k];
        float v = accP * G + D0 * hw[17] + D1 * hw[16] + D2 * hw[15] + D3 * hw[14] + D4 * hw[13];
        if (t == 0 && hi == 0) v += hb[0];
#pragma unroll
        for (int off = 32; off > 0; off >>= 1) v += __shfl_xor(v, off);
        if ((t & 63) == 0) atomicAdd(&out[b], v);
    }
}

extern "C" void kernel_launch(void* const* d_in, const int* in_sizes, int n_in,
                              void* d_out, int out_size, void* d_ws, size_t ws_size,
                              hipStream_t stream)
{
    float* re            = (float*)d_in[0];
    float* im            = (float*)d_in[1];
    const float* params  = (const float*)d_in[2];
    const float* hw      = (const float*)d_in[3];
    const float* hb      = (const float*)d_in[4];
    float* out           = (float*)d_out;
    (void)in_sizes; (void)n_in; (void)d_ws; (void)ws_size;

    hipMemsetAsync(out, 0, (size_t)out_size * sizeof(float), stream);

    const dim3 grid(4096), blk(128);
    for (int l = 0; l < 3; ++l) {
        passB_k<<<grid, blk, 0, stream>>>(re, im, params, l);
        if (l < 2) passA_k<false><<<grid, blk, 0, stream>>>(re, im, params, l, nullptr, nullptr, nullptr);
        else       passA_k<true ><<<grid, blk, 0, stream>>>(re, im, params, l, hw, hb, out);
    }
}

// Round 2
// 442.829 us; speedup vs baseline: 1.0095x; 1.0095x over previous
//
#include <hip/hip_runtime.h>

// Quantum circuit simulator: 18 wires, 3 layers, batch 64.
// State kept in-place as SoA planes in d_in[0] (re) / d_in[1] (im).
// Wire w <-> bit p = 17-w. Per layer (exact rewrite via commutation):
//   PassB: SQ(bits 17..11), CNOT(17,16)..(12,11)   [touches bits 11..17]
//   PassA: SQ(bits 10..0),  CNOT(11,10)..(1,0)     [touches bits 0..11]
// SQ = fused RY(θy) then RZ(θz) with RZ global phase dropped (output is |amp|^2 only).
// R2 change: SINGLE shared LDS buffer, re/im transposed sequentially.
// LDS 35.3 KB -> 17.6 KB => 9 blocks/CU (18 waves) instead of 4 (8 waves).

static __device__ __forceinline__ int phys(int m) {
    // LDS skew: keeps 16B alignment (multiple-of-4 shift), breaks power-of-2 bank strides
    return m + 4 * ((m >> 6) + (m >> 9));
}

template<int J>
__device__ __forceinline__ void sqg(float* ar, float* ai, float c, float s, float pc, float ps) {
#pragma unroll
    for (int r = 0; r < 32; ++r) {
        if (((r >> J) & 1) == 0) {
            const int r1 = r + (1 << J);
            const float a0r = ar[r], a0i = ai[r], a1r = ar[r1], a1i = ai[r1];
            ar[r] = fmaf(c, a0r, -(s * a1r));
            ai[r] = fmaf(c, a0i, -(s * a1i));
            const float t1r = fmaf(s, a0r, c * a1r);
            const float t1i = fmaf(s, a0i, c * a1i);
            ar[r1] = fmaf(pc, t1r, -(ps * t1i));
            ai[r1] = fmaf(pc, t1i,  (ps * t1r));
        }
    }
}

template<int JC, int JT>
__device__ __forceinline__ void cnotg(float* ar, float* ai) {
#pragma unroll
    for (int r = 0; r < 32; ++r) {
        if (((r >> JC) & 1) == 1 && ((r >> JT) & 1) == 0) {
            const int r1 = r + (1 << JT);
            float tr = ar[r]; ar[r] = ar[r1]; ar[r1] = tr;
            float ti = ai[r]; ai[r] = ai[r1]; ai[r1] = ti;
        }
    }
}

// ---------------- Pass B: bits 11..17 ----------------
// Block covers bits {11..17} x filler {0..4}; fixed bits: batch, mid = bits 5..10.
__global__ __launch_bounds__(128) void passB_k(float* __restrict__ re, float* __restrict__ im,
                                               const float* __restrict__ params, int layer)
{
    __shared__ float lds[4376];
    const int t    = threadIdx.x;
    const int b    = blockIdx.x >> 6;
    const int mid  = blockIdx.x & 63;
    const int base = (b << 18) | (mid << 5);

    // coeffs for bit 11+k  (wire 6-k)
    float C[7], S[7], PC[7], PS[7];
    const float* pl = params + layer * 36;
#pragma unroll
    for (int k = 0; k < 7; ++k) {
        const int w = 6 - k;
        __sincosf(0.5f * pl[w], &S[k], &C[k]);
        __sincosf(pl[18 + w], &PS[k], &PC[k]);
    }

    float ar[32], ai[32];
    // B1 layout: reg = bits 13..17 ; cols: t&31 = bits 0..4, t>>5 = bits 11,12
#pragma unroll
    for (int r = 0; r < 32; ++r) {
        const int n = base + (r << 13) + ((t >> 5) << 11) + (t & 31);
        ar[r] = re[n]; ai[r] = im[n];
    }
    // SQ(17..13), CNOT(17,16)..(14,13)   (reg bit j = global bit 13+j = coeff j+2)
    sqg<4>(ar, ai, C[6], S[6], PC[6], PS[6]);
    sqg<3>(ar, ai, C[5], S[5], PC[5], PS[5]);
    sqg<2>(ar, ai, C[4], S[4], PC[4], PS[4]);
    sqg<1>(ar, ai, C[3], S[3], PC[3], PS[3]);
    sqg<0>(ar, ai, C[2], S[2], PC[2], PS[2]);
    cnotg<4,3>(ar, ai);
    cnotg<3,2>(ar, ai);
    cnotg<2,1>(ar, ai);
    cnotg<1,0>(ar, ai);

    // T1: local m = (bits 11..17)<<5 | (bits 0..4) = r<<7 | t
    // B2 layout: reg r&3 = bits 0,1 ; reg r>>2 = bits 11,12,13 ; cols: t&7 = bits 2..4, t>>3 = bits 14..17
    // re plane:
#pragma unroll
    for (int r = 0; r < 32; ++r) lds[phys((r << 7) | t)] = ar[r];
    __syncthreads();
#pragma unroll
    for (int g = 0; g < 8; ++g) {
        const int m = ((t >> 3) << 8) | (g << 5) | ((t & 7) << 2);
        const float4 v = *(const float4*)&lds[phys(m)];
        ar[4*g+0] = v.x; ar[4*g+1] = v.y; ar[4*g+2] = v.z; ar[4*g+3] = v.w;
    }
    __syncthreads();
    // im plane:
#pragma unroll
    for (int r = 0; r < 32; ++r) lds[phys((r << 7) | t)] = ai[r];
    __syncthreads();
#pragma unroll
    for (int g = 0; g < 8; ++g) {
        const int m = ((t >> 3) << 8) | (g << 5) | ((t & 7) << 2);
        const float4 v = *(const float4*)&lds[phys(m)];
        ai[4*g+0] = v.x; ai[4*g+1] = v.y; ai[4*g+2] = v.z; ai[4*g+3] = v.w;
    }

    // SQ(12)=reg3, SQ(11)=reg2, CNOT(13,12)=<4,3>, CNOT(12,11)=<3,2>
    sqg<3>(ar, ai, C[1], S[1], PC[1], PS[1]);
    sqg<2>(ar, ai, C[0], S[0], PC[0], PS[0]);
    cnotg<4,3>(ar, ai);
    cnotg<3,2>(ar, ai);

    // store directly from B2 layout (float4, contiguous 32-float runs per 8 lanes)
#pragma unroll
    for (int g = 0; g < 8; ++g) {
        const int n = base + ((t >> 3) << 14) + (g << 11) + ((t & 7) << 2);
        *(float4*)&re[n] = make_float4(ar[4*g+0], ar[4*g+1], ar[4*g+2], ar[4*g+3]);
        *(float4*)&im[n] = make_float4(ai[4*g+0], ai[4*g+1], ai[4*g+2], ai[4*g+3]);
    }
}

// ---------------- Pass A: bits 0..11 ----------------
// Block covers bits {0..11}; fixed bits: batch, hi = bits 12..17.
template<bool FINAL>
__global__ __launch_bounds__(128) void passA_k(float* __restrict__ re, float* __restrict__ im,
                                               const float* __restrict__ params, int layer,
                                               const float* __restrict__ hw,
                                               const float* __restrict__ hb,
                                               float* __restrict__ out)
{
    __shared__ float lds[4376];
    const int t    = threadIdx.x;
    const int b    = blockIdx.x >> 6;
    const int hi   = blockIdx.x & 63;
    const int base = (b << 18) | (hi << 12);

    // coeffs for bit p (wire 17-p), p = 0..10
    float C[11], S[11], PC[11], PS[11];
    const float* pl = params + layer * 36;
#pragma unroll
    for (int p = 0; p < 11; ++p) {
        const int w = 17 - p;
        __sincosf(0.5f * pl[w], &S[p], &C[p]);
        __sincosf(pl[18 + w], &PS[p], &PC[p]);
    }

    float ar[32], ai[32];
    // A1 layout: reg = bits 7..11 ; cols t = bits 0..6
#pragma unroll
    for (int r = 0; r < 32; ++r) {
        const int n = base + (r << 7) + t;
        ar[r] = re[n]; ai[r] = im[n];
    }
    // SQ(10..7), CNOT(11,10)..(8,7)   (reg j = global 7+j)
    sqg<3>(ar, ai, C[10], S[10], PC[10], PS[10]);
    sqg<2>(ar, ai, C[9],  S[9],  PC[9],  PS[9]);
    sqg<1>(ar, ai, C[8],  S[8],  PC[8],  PS[8]);
    sqg<0>(ar, ai, C[7],  S[7],  PC[7],  PS[7]);
    cnotg<4,3>(ar, ai); cnotg<3,2>(ar, ai); cnotg<2,1>(ar, ai); cnotg<1,0>(ar, ai);

    // T1: A1 m=(r<<7)|t  ->  A2 m=((t>>3)<<8)|(r<<3)|(t&7)
    // A2 layout: reg = bits 3..7 ; cols: t&7 = bits 0..2, t>>3 = bits 8..11
#pragma unroll
    for (int r = 0; r < 32; ++r) lds[phys((r << 7) | t)] = ar[r];
    __syncthreads();
#pragma unroll
    for (int r = 0; r < 32; ++r) {
        const int m = ((t >> 3) << 8) | (r << 3) | (t & 7);
        ar[r] = lds[phys(m)];
    }
    __syncthreads();
#pragma unroll
    for (int r = 0; r < 32; ++r) lds[phys((r << 7) | t)] = ai[r];
    __syncthreads();
#pragma unroll
    for (int r = 0; r < 32; ++r) {
        const int m = ((t >> 3) << 8) | (r << 3) | (t & 7);
        ai[r] = lds[phys(m)];
    }

    // SQ(6..3), CNOT(7,6)..(4,3)   (reg j = global 3+j)
    sqg<3>(ar, ai, C[6], S[6], PC[6], PS[6]);
    sqg<2>(ar, ai, C[5], S[5], PC[5], PS[5]);
    sqg<1>(ar, ai, C[4], S[4], PC[4], PS[4]);
    sqg<0>(ar, ai, C[3], S[3], PC[3], PS[3]);
    cnotg<4,3>(ar, ai); cnotg<3,2>(ar, ai); cnotg<2,1>(ar, ai); cnotg<1,0>(ar, ai);

    // T2: A2 m=((t>>3)<<8)|(r<<3)|(t&7)  ->  A3 m=(t<<5)|r  (float4 reads)
    // A3 layout: reg = bits 0..4 ; cols t = bits 5..11
    __syncthreads();
#pragma unroll
    for (int r = 0; r < 32; ++r) {
        const int m = ((t >> 3) << 8) | (r << 3) | (t & 7);
        lds[phys(m)] = ar[r];
    }
    __syncthreads();
#pragma unroll
    for (int g = 0; g < 8; ++g) {
        const int m = (t << 5) | (g << 2);
        const float4 v = *(const float4*)&lds[phys(m)];
        ar[4*g+0] = v.x; ar[4*g+1] = v.y; ar[4*g+2] = v.z; ar[4*g+3] = v.w;
    }
    __syncthreads();
#pragma unroll
    for (int r = 0; r < 32; ++r) {
        const int m = ((t >> 3) << 8) | (r << 3) | (t & 7);
        lds[phys(m)] = ai[r];
    }
    __syncthreads();
#pragma unroll
    for (int g = 0; g < 8; ++g) {
        const int m = (t << 5) | (g << 2);
        const float4 v = *(const float4*)&lds[phys(m)];
        ai[4*g+0] = v.x; ai[4*g+1] = v.y; ai[4*g+2] = v.z; ai[4*g+3] = v.w;
    }

    // SQ(2..0), CNOT(3,2),(2,1),(1,0)  (reg j = global j)
    sqg<2>(ar, ai, C[2], S[2], PC[2], PS[2]);
    sqg<1>(ar, ai, C[1], S[1], PC[1], PS[1]);
    sqg<0>(ar, ai, C[0], S[0], PC[0], PS[0]);
    cnotg<3,2>(ar, ai); cnotg<2,1>(ar, ai); cnotg<1,0>(ar, ai);

    if (!FINAL) {
        // T3: A3 (t<<5)|(g<<2)  ->  coalesced store layout (g<<9)|(t<<2)
        __syncthreads();
#pragma unroll
        for (int g = 0; g < 8; ++g) {
            const int m = (t << 5) | (g << 2);
            *(float4*)&lds[phys(m)] = make_float4(ar[4*g+0], ar[4*g+1], ar[4*g+2], ar[4*g+3]);
        }
        __syncthreads();
#pragma unroll
        for (int g = 0; g < 8; ++g) {
            const int m = (g << 9) | (t << 2);
            const float4 v = *(const float4*)&lds[phys(m)];
            const int n = base + (g << 9) + (t << 2);
            *(float4*)&re[n] = v;
        }
        __syncthreads();
#pragma unroll
        for (int g = 0; g < 8; ++g) {
            const int m = (t << 5) | (g << 2);
            *(float4*)&lds[phys(m)] = make_float4(ai[4*g+0], ai[4*g+1], ai[4*g+2], ai[4*g+3]);
        }
        __syncthreads();
#pragma unroll
        for (int g = 0; g < 8; ++g) {
            const int m = (g << 9) | (t << 2);
            const float4 v = *(const float4*)&lds[phys(m)];
            const int n = base + (g << 9) + (t << 2);
            *(float4*)&im[n] = v;
        }
    } else {
        // expval(Z_w) for all wires + linear head, from A3 layout: n = base | (t<<5) | r
        float accP = 0.f, D0 = 0.f, D1 = 0.f, D2 = 0.f, D3 = 0.f, D4 = 0.f;
#pragma unroll
        for (int r = 0; r < 32; ++r) {
            const float p = ar[r] * ar[r] + ai[r] * ai[r];
            accP += p;
            if (r & 1)  D0 -= p; else D0 += p;
            if (r & 2)  D1 -= p; else D1 += p;
            if (r & 4)  D2 -= p; else D2 += p;
            if (r & 8)  D3 -= p; else D3 += p;
            if (r & 16) D4 -= p; else D4 += p;
        }
        float G = 0.f;
#pragma unroll
        for (int k = 0; k < 7; ++k)   // n bit 5+k = t bit k, wire 12-k
            G += ((t >> k) & 1) ? -hw[12 - k] : hw[12 - k];
#pragma unroll
        for (int k = 0; k < 6; ++k)   // n bit 12+k = hi bit k, wire 5-k
            G += ((hi >> k) & 1) ? -hw[5 - k] : hw[5 - k];
        float v = accP * G + D0 * hw[17] + D1 * hw[16] + D2 * hw[15] + D3 * hw[14] + D4 * hw[13];
        if (t == 0 && hi == 0) v += hb[0];
#pragma unroll
        for (int off = 32; off > 0; off >>= 1) v += __shfl_xor(v, off);
        if ((t & 63) == 0) atomicAdd(&out[b], v);
    }
}

extern "C" void kernel_launch(void* const* d_in, const int* in_sizes, int n_in,
                              void* d_out, int out_size, void* d_ws, size_t ws_size,
                              hipStream_t stream)
{
    float* re            = (float*)d_in[0];
    float* im            = (float*)d_in[1];
    const float* params  = (const float*)d_in[2];
    const float* hw      = (const float*)d_in[3];
    const float* hb      = (const float*)d_in[4];
    float* out           = (float*)d_out;
    (void)in_sizes; (void)n_in; (void)d_ws; (void)ws_size;

    hipMemsetAsync(out, 0, (size_t)out_size * sizeof(float), stream);

    const dim3 grid(4096), blk(128);
    for (int l = 0; l < 3; ++l) {
        passB_k<<<grid, blk, 0, stream>>>(re, im, params, l);
        if (l < 2) passA_k<false><<<grid, blk, 0, stream>>>(re, im, params, l, nullptr, nullptr, nullptr);
        else       passA_k<true ><<<grid, blk, 0, stream>>>(re, im, params, l, hw, hb, out);
    }
}